// Round 1
// baseline (448.124 us; speedup 1.0000x reference)
//
#include <hip/hip_runtime.h>
#include <math.h>

#define N_NODES 50000
#define N_EDGES 800000
#define IN_DIM  128
#define HID_DIM 64

// ---------------- init: deg=1 (self-loop weight), zero accumulators ----------
__global__ void init_kernel(float* __restrict__ deg, float* __restrict__ acc1,
                            float* __restrict__ acc2) {
    int i = blockIdx.x * blockDim.x + threadIdx.x;
    if (i < N_NODES * HID_DIM) acc1[i] = 0.0f;
    if (i < N_NODES) { deg[i] = 1.0f; acc2[i] = 0.0f; }
}

// ---------------- degree accumulation over edges -----------------------------
__global__ void deg_kernel(const int* __restrict__ dst, const float* __restrict__ ew,
                           float* __restrict__ deg) {
    int e = blockIdx.x * blockDim.x + threadIdx.x;
    if (e < N_EDGES) atomicAdd(&deg[dst[e]], ew[e]);
}

// ---------------- dinv = rsqrt(deg), in place --------------------------------
__global__ void dinv_kernel(float* __restrict__ deg) {
    int n = blockIdx.x * blockDim.x + threadIdx.x;
    if (n < N_NODES) {
        float d = deg[n];
        deg[n] = (d > 0.0f) ? rsqrtf(d) : 0.0f;
    }
}

// ---------------- h1s[n][j] = (x[n] @ W1[:,j]) * dinv[n] ---------------------
// one wave per node: lane j computes column j (W1 reads coalesced, x broadcast)
__global__ void gemm1_kernel(const float* __restrict__ x, const float* __restrict__ W1,
                             const float* __restrict__ dinv, float* __restrict__ h1s) {
    int wave = (blockIdx.x * blockDim.x + threadIdx.x) >> 6;
    int lane = threadIdx.x & 63;
    if (wave >= N_NODES) return;
    const float* xr = x + (long)wave * IN_DIM;
    float acc = 0.0f;
#pragma unroll 8
    for (int k = 0; k < IN_DIM; ++k)
        acc += xr[k] * W1[k * HID_DIM + lane];
    h1s[wave * HID_DIM + lane] = acc * dinv[wave];
}

// ---------------- layer-1 edge scatter: acc1[dst] += ew * h1s[src] -----------
// one wave per edge: lane j handles column j (256B contiguous gather + atomic)
__global__ void scatter1_kernel(const int* __restrict__ src, const int* __restrict__ dst,
                                const float* __restrict__ ew, const float* __restrict__ h1s,
                                float* __restrict__ acc1) {
    int t = blockIdx.x * blockDim.x + threadIdx.x;
    int e = t >> 6;
    int lane = t & 63;
    if (e >= N_EDGES) return;
    int s = src[e];
    int d = dst[e];
    float w = ew[e];
    atomicAdd(&acc1[d * HID_DIM + lane], w * h1s[s * HID_DIM + lane]);
}

// ---------------- finalize layer 1 + relu + layer-2 GEMV ---------------------
// z1 = dinv*(acc1 + h1s) + b1 ; h = relu(z1) ; h2s[n] = (h @ W2) * dinv[n]
__global__ void layer2_kernel(const float* __restrict__ acc1, const float* __restrict__ h1s,
                              const float* __restrict__ dinv, const float* __restrict__ b1,
                              const float* __restrict__ W2, float* __restrict__ h2s) {
    int wave = (blockIdx.x * blockDim.x + threadIdx.x) >> 6;
    int lane = threadIdx.x & 63;
    if (wave >= N_NODES) return;
    float di = dinv[wave];
    int idx = wave * HID_DIM + lane;
    float z = di * (acc1[idx] + h1s[idx]) + b1[lane];
    float h = fmaxf(z, 0.0f);
    float v = h * W2[lane];
#pragma unroll
    for (int off = 32; off > 0; off >>= 1)
        v += __shfl_down(v, off, 64);
    if (lane == 0) h2s[wave] = v * di;
}

// ---------------- layer-2 edge scatter (scalar messages) ---------------------
__global__ void scatter2_kernel(const int* __restrict__ src, const int* __restrict__ dst,
                                const float* __restrict__ ew, const float* __restrict__ h2s,
                                float* __restrict__ acc2) {
    int e = blockIdx.x * blockDim.x + threadIdx.x;
    if (e < N_EDGES) atomicAdd(&acc2[dst[e]], ew[e] * h2s[src[e]]);
}

// ---------------- finalize: sigmoid(dinv*(acc2 + h2s) + b2) ------------------
__global__ void final_kernel(const float* __restrict__ acc2, const float* __restrict__ h2s,
                             const float* __restrict__ dinv, const float* __restrict__ b2,
                             float* __restrict__ out) {
    int n = blockIdx.x * blockDim.x + threadIdx.x;
    if (n < N_NODES) {
        float z = dinv[n] * (acc2[n] + h2s[n]) + b2[0];
        out[n] = 1.0f / (1.0f + expf(-z));
    }
}

extern "C" void kernel_launch(void* const* d_in, const int* in_sizes, int n_in,
                              void* d_out, int out_size, void* d_ws, size_t ws_size,
                              hipStream_t stream) {
    const float* x  = (const float*)d_in[0];
    const int*   ei = (const int*)d_in[1];
    const float* ew = (const float*)d_in[2];
    const float* W1 = (const float*)d_in[3];
    const float* b1 = (const float*)d_in[4];
    const float* W2 = (const float*)d_in[5];
    const float* b2 = (const float*)d_in[6];
    float* out = (float*)d_out;

    const int* src = ei;            // edge_index[0]
    const int* dst = ei + N_EDGES;  // edge_index[1]

    // workspace layout (floats)
    float* ws   = (float*)d_ws;
    float* dinv = ws;                       // [N]  (deg, then rsqrt in place)
    float* h2s  = ws + N_NODES;             // [N]
    float* acc2 = ws + 2 * N_NODES;         // [N]
    float* h1s  = ws + 3 * N_NODES;         // [N*64]
    float* acc1 = h1s + N_NODES * HID_DIM;  // [N*64]

    const int B = 256;

    // init
    {
        int total = N_NODES * HID_DIM;
        init_kernel<<<(total + B - 1) / B, B, 0, stream>>>(dinv, acc1, acc2);
    }
    // degree
    deg_kernel<<<(N_EDGES + B - 1) / B, B, 0, stream>>>(dst, ew, dinv);
    // rsqrt
    dinv_kernel<<<(N_NODES + B - 1) / B, B, 0, stream>>>(dinv);
    // h1s = (x @ W1) * dinv   (wave per node)
    {
        int waves = N_NODES;
        int blocks = (waves * 64 + B - 1) / B;
        gemm1_kernel<<<blocks, B, 0, stream>>>(x, W1, dinv, h1s);
    }
    // layer-1 scatter (wave per edge)
    {
        long threads = (long)N_EDGES * 64;
        int blocks = (int)((threads + B - 1) / B);
        scatter1_kernel<<<blocks, B, 0, stream>>>(src, dst, ew, h1s, acc1);
    }
    // finalize layer1 + relu + GEMV layer2 (wave per node)
    {
        int blocks = (N_NODES * 64 + B - 1) / B;
        layer2_kernel<<<blocks, B, 0, stream>>>(acc1, h1s, dinv, b1, W2, h2s);
    }
    // layer-2 scatter
    scatter2_kernel<<<(N_EDGES + B - 1) / B, B, 0, stream>>>(src, dst, ew, h2s, acc2);
    // sigmoid
    final_kernel<<<(N_NODES + B - 1) / B, B, 0, stream>>>(acc2, h2s, dinv, b2, out);
}

// Round 2
// 297.167 us; speedup vs baseline: 1.5080x; 1.5080x over previous
//
#include <hip/hip_runtime.h>
#include <math.h>

#define N_NODES 50000
#define N_EDGES 800000
#define IN_DIM  128
#define HID_DIM 64

#define SCAN_B   256
#define SCAN_NB  ((N_NODES + SCAN_B - 1) / SCAN_B)   // 196

// ---------------- init: zero counts & cursor, start[0]=0 ---------------------
__global__ void init_kernel(int* __restrict__ counts, int* __restrict__ cursor,
                            int* __restrict__ start) {
    int i = blockIdx.x * blockDim.x + threadIdx.x;
    if (i < N_NODES) { counts[i] = 0; cursor[i] = 0; }
    if (i == 0) start[0] = 0;
}

// ---------------- histogram of dst --------------------------------------------
__global__ void hist_kernel(const int* __restrict__ dst, int* __restrict__ counts) {
    int e = blockIdx.x * blockDim.x + threadIdx.x;
    if (e < N_EDGES) atomicAdd(&counts[dst[e]], 1);
}

// ---------------- scan step 1: per-block inclusive scan -----------------------
__global__ void scan1_kernel(const int* __restrict__ counts, int* __restrict__ start,
                             int* __restrict__ bsum) {
    __shared__ int s[SCAN_B];
    int tid = threadIdx.x;
    int i = blockIdx.x * SCAN_B + tid;
    int v = (i < N_NODES) ? counts[i] : 0;
    s[tid] = v;
    __syncthreads();
#pragma unroll
    for (int off = 1; off < SCAN_B; off <<= 1) {
        int t = (tid >= off) ? s[tid - off] : 0;
        __syncthreads();
        s[tid] += t;
        __syncthreads();
    }
    if (i < N_NODES) start[i + 1] = s[tid];          // inclusive, block-local
    if (tid == SCAN_B - 1) bsum[blockIdx.x] = s[tid];
}

// ---------------- scan step 2: exclusive scan of block sums -------------------
__global__ void scan2_kernel(const int* __restrict__ bsum, int* __restrict__ boff) {
    __shared__ int s[SCAN_B];
    int tid = threadIdx.x;
    int v = (tid < SCAN_NB) ? bsum[tid] : 0;
    s[tid] = v;
    __syncthreads();
#pragma unroll
    for (int off = 1; off < SCAN_B; off <<= 1) {
        int t = (tid >= off) ? s[tid - off] : 0;
        __syncthreads();
        s[tid] += t;
        __syncthreads();
    }
    if (tid < SCAN_NB) boff[tid] = s[tid] - v;       // exclusive
}

// ---------------- scan step 3: add block offsets ------------------------------
__global__ void scan3_kernel(int* __restrict__ start, const int* __restrict__ boff) {
    int i = blockIdx.x * SCAN_B + threadIdx.x;
    if (i < N_NODES) start[i + 1] += boff[blockIdx.x];
}

// ---------------- scatter edges into dst-sorted arrays ------------------------
__global__ void sort_kernel(const int* __restrict__ src, const int* __restrict__ dst,
                            const float* __restrict__ ew, const int* __restrict__ start,
                            int* __restrict__ cursor, int* __restrict__ src_s,
                            float* __restrict__ ew_s) {
    int e = blockIdx.x * blockDim.x + threadIdx.x;
    if (e >= N_EDGES) return;
    int d = dst[e];
    int pos = start[d] + atomicAdd(&cursor[d], 1);
    src_s[pos] = src[e];
    ew_s[pos]  = ew[e];
}

// ---------------- deg from segments -> dinv -----------------------------------
__global__ void degdinv_kernel(const int* __restrict__ start, const float* __restrict__ ew_s,
                               float* __restrict__ dinv) {
    int n = blockIdx.x * blockDim.x + threadIdx.x;
    if (n >= N_NODES) return;
    int s0 = start[n], s1 = start[n + 1];
    float deg = 1.0f;                                  // self-loop weight
    for (int t = s0; t < s1; ++t) deg += ew_s[t];
    dinv[n] = rsqrtf(deg);
}

// ---------------- h1s = (x @ W1) * dinv  (W1 in LDS, 4 nodes/block) -----------
__global__ __launch_bounds__(256)
void gemm1_kernel(const float* __restrict__ x, const float* __restrict__ W1,
                  const float* __restrict__ dinv, float* __restrict__ h1s) {
    __shared__ float w1s[IN_DIM * HID_DIM];  // 32 KB
    __shared__ float xs[4][IN_DIM];          // 2 KB
    int tid = threadIdx.x;
    const float4* W4 = (const float4*)W1;
    float4* w1s4 = (float4*)w1s;
#pragma unroll
    for (int i = 0; i < 8; ++i) w1s4[tid + 256 * i] = W4[tid + 256 * i];
    int wl = tid >> 6;
    int lane = tid & 63;
    int node = blockIdx.x * 4 + wl;
    if (node < N_NODES) {
        const float2* xr = (const float2*)(x + (long)node * IN_DIM);
        ((float2*)xs[wl])[lane] = xr[lane];
    }
    __syncthreads();
    if (node >= N_NODES) return;
    float a0 = 0.f, a1 = 0.f, a2 = 0.f, a3 = 0.f;
#pragma unroll
    for (int k = 0; k < IN_DIM; k += 4) {
        float4 xv = *(const float4*)&xs[wl][k];        // broadcast read
        a0 += xv.x * w1s[(k + 0) * HID_DIM + lane];
        a1 += xv.y * w1s[(k + 1) * HID_DIM + lane];
        a2 += xv.z * w1s[(k + 2) * HID_DIM + lane];
        a3 += xv.w * w1s[(k + 3) * HID_DIM + lane];
    }
    h1s[node * HID_DIM + lane] = (a0 + a1 + a2 + a3) * dinv[node];
}

// ---------------- fused: segmented gather L1 + finalize + relu + W2 GEMV ------
// wave per node, lane = column
__global__ void gather1_layer2_kernel(const int* __restrict__ start, const int* __restrict__ src_s,
                                      const float* __restrict__ ew_s, const float* __restrict__ h1s,
                                      const float* __restrict__ dinv, const float* __restrict__ b1,
                                      const float* __restrict__ W2, float* __restrict__ h2s) {
    int wave = (blockIdx.x * blockDim.x + threadIdx.x) >> 6;
    int lane = threadIdx.x & 63;
    if (wave >= N_NODES) return;
    int s0 = start[wave], s1 = start[wave + 1];
    float acc0 = 0.f, acc1 = 0.f;
    int t = s0;
    for (; t + 1 < s1; t += 2) {
        int   sa = src_s[t],     sb = src_s[t + 1];
        float wa = ew_s[t],      wb = ew_s[t + 1];
        float va = h1s[sa * HID_DIM + lane];
        float vb = h1s[sb * HID_DIM + lane];
        acc0 += wa * va;
        acc1 += wb * vb;
    }
    if (t < s1)
        acc0 += ew_s[t] * h1s[src_s[t] * HID_DIM + lane];
    float di = dinv[wave];
    float self = h1s[wave * HID_DIM + lane];
    float z = di * (acc0 + acc1 + self) + b1[lane];
    float h = fmaxf(z, 0.0f);
    float v = h * W2[lane];
#pragma unroll
    for (int off = 32; off > 0; off >>= 1)
        v += __shfl_down(v, off, 64);
    if (lane == 0) h2s[wave] = v * di;
}

// ---------------- fused: segmented gather L2 + sigmoid ------------------------
__global__ void gather2_final_kernel(const int* __restrict__ start, const int* __restrict__ src_s,
                                     const float* __restrict__ ew_s, const float* __restrict__ h2s,
                                     const float* __restrict__ dinv, const float* __restrict__ b2,
                                     float* __restrict__ out) {
    int n = blockIdx.x * blockDim.x + threadIdx.x;
    if (n >= N_NODES) return;
    int s0 = start[n], s1 = start[n + 1];
    float acc = 0.0f;
    for (int t = s0; t < s1; ++t)
        acc += ew_s[t] * h2s[src_s[t]];
    float z = dinv[n] * (acc + h2s[n]) + b2[0];
    out[n] = 1.0f / (1.0f + expf(-z));
}

extern "C" void kernel_launch(void* const* d_in, const int* in_sizes, int n_in,
                              void* d_out, int out_size, void* d_ws, size_t ws_size,
                              hipStream_t stream) {
    const float* x  = (const float*)d_in[0];
    const int*   ei = (const int*)d_in[1];
    const float* ew = (const float*)d_in[2];
    const float* W1 = (const float*)d_in[3];
    const float* b1 = (const float*)d_in[4];
    const float* W2 = (const float*)d_in[5];
    const float* b2 = (const float*)d_in[6];
    float* out = (float*)d_out;

    const int* src = ei;
    const int* dst = ei + N_EDGES;

    // workspace layout
    char* ws = (char*)d_ws;
    int*   start  = (int*)ws;                 ws += (N_NODES + 1) * sizeof(int);
    int*   counts = (int*)ws;                 ws += N_NODES * sizeof(int);
    int*   cursor = (int*)ws;                 ws += N_NODES * sizeof(int);
    int*   bsum   = (int*)ws;                 ws += SCAN_B * sizeof(int);
    int*   boff   = (int*)ws;                 ws += SCAN_B * sizeof(int);
    int*   src_s  = (int*)ws;                 ws += N_EDGES * sizeof(int);
    float* ew_s   = (float*)ws;               ws += N_EDGES * sizeof(float);
    float* dinv   = (float*)ws;               ws += N_NODES * sizeof(float);
    float* h2s    = (float*)ws;               ws += N_NODES * sizeof(float);
    float* h1s    = (float*)ws;               // N_NODES * HID_DIM floats

    const int B = 256;
    const int nbN = (N_NODES + B - 1) / B;    // 196
    const int nbE = (N_EDGES + B - 1) / B;

    init_kernel<<<nbN, B, 0, stream>>>(counts, cursor, start);
    hist_kernel<<<nbE, B, 0, stream>>>(dst, counts);
    scan1_kernel<<<SCAN_NB, SCAN_B, 0, stream>>>(counts, start, bsum);
    scan2_kernel<<<1, SCAN_B, 0, stream>>>(bsum, boff);
    scan3_kernel<<<SCAN_NB, SCAN_B, 0, stream>>>(start, boff);
    sort_kernel<<<nbE, B, 0, stream>>>(src, dst, ew, start, cursor, src_s, ew_s);
    degdinv_kernel<<<nbN, B, 0, stream>>>(start, ew_s, dinv);
    gemm1_kernel<<<(N_NODES + 3) / 4, 256, 0, stream>>>(x, W1, dinv, h1s);
    {
        long threads = (long)N_NODES * 64;
        int blocks = (int)((threads + B - 1) / B);
        gather1_layer2_kernel<<<blocks, B, 0, stream>>>(start, src_s, ew_s, h1s, dinv, b1, W2, h2s);
    }
    gather2_final_kernel<<<nbN, B, 0, stream>>>(start, src_s, ew_s, h2s, dinv, b2, out);
}

// Round 3
// 268.353 us; speedup vs baseline: 1.6699x; 1.1074x over previous
//
#include <hip/hip_runtime.h>
#include <hip/hip_bf16.h>
#include <math.h>

#define N_NODES 50000
#define N_EDGES 800000
#define IN_DIM  128
#define HID_DIM 64

#define SCAN_B   256
#define SCAN_NB  ((N_NODES + SCAN_B - 1) / SCAN_B)   // 196

// ---------------- init: zero counts/cursor, degf=1 (self-loop), start[0]=0 ---
__global__ void init_kernel(int* __restrict__ counts, int* __restrict__ cursor,
                            float* __restrict__ degf, int* __restrict__ start) {
    int i = blockIdx.x * blockDim.x + threadIdx.x;
    if (i < N_NODES) { counts[i] = 0; cursor[i] = 0; degf[i] = 1.0f; }
    if (i == 0) start[0] = 0;
}

// ---------------- histogram of dst + weighted degree --------------------------
__global__ void hist_kernel(const int* __restrict__ dst, const float* __restrict__ ew,
                            int* __restrict__ counts, float* __restrict__ degf) {
    int e = blockIdx.x * blockDim.x + threadIdx.x;
    if (e < N_EDGES) {
        int d = dst[e];
        atomicAdd(&counts[d], 1);
        atomicAdd(&degf[d], ew[e]);
    }
}

// ---------------- scan step 1: per-block inclusive scan -----------------------
__global__ void scan1_kernel(const int* __restrict__ counts, int* __restrict__ start,
                             int* __restrict__ bsum) {
    __shared__ int s[SCAN_B];
    int tid = threadIdx.x;
    int i = blockIdx.x * SCAN_B + tid;
    int v = (i < N_NODES) ? counts[i] : 0;
    s[tid] = v;
    __syncthreads();
#pragma unroll
    for (int off = 1; off < SCAN_B; off <<= 1) {
        int t = (tid >= off) ? s[tid - off] : 0;
        __syncthreads();
        s[tid] += t;
        __syncthreads();
    }
    if (i < N_NODES) start[i + 1] = s[tid];
    if (tid == SCAN_B - 1) bsum[blockIdx.x] = s[tid];
}

// ---------------- scan step 2: exclusive scan of block sums -------------------
__global__ void scan2_kernel(const int* __restrict__ bsum, int* __restrict__ boff) {
    __shared__ int s[SCAN_B];
    int tid = threadIdx.x;
    int v = (tid < SCAN_NB) ? bsum[tid] : 0;
    s[tid] = v;
    __syncthreads();
#pragma unroll
    for (int off = 1; off < SCAN_B; off <<= 1) {
        int t = (tid >= off) ? s[tid - off] : 0;
        __syncthreads();
        s[tid] += t;
        __syncthreads();
    }
    if (tid < SCAN_NB) boff[tid] = s[tid] - v;
}

// ---------------- scan step 3: add block offsets ------------------------------
__global__ void scan3_kernel(int* __restrict__ start, const int* __restrict__ boff) {
    int i = blockIdx.x * SCAN_B + threadIdx.x;
    if (i < N_NODES) start[i + 1] += boff[blockIdx.x];
}

// ---------------- scatter edges into dst-sorted packed array ------------------
__global__ void sort_kernel(const int* __restrict__ src, const int* __restrict__ dst,
                            const float* __restrict__ ew, const int* __restrict__ start,
                            int* __restrict__ cursor, int2* __restrict__ edge_s) {
    int e = blockIdx.x * blockDim.x + threadIdx.x;
    if (e >= N_EDGES) return;
    int d = dst[e];
    int pos = start[d] + atomicAdd(&cursor[d], 1);
    edge_s[pos] = make_int2(src[e], __float_as_int(ew[e]));
}

// ---------------- h1b = bf16((x @ W1) * dinv); also emits dinv ----------------
// 16 nodes/block, 4 nodes/wave: W1 in LDS amortized, 4 FMAs per LDS w-read.
// 50000 = 3125 * 16 exactly, so no bounds checks needed.
__global__ __launch_bounds__(256)
void gemm1_kernel(const float* __restrict__ x, const float* __restrict__ W1,
                  const float* __restrict__ degf, __hip_bfloat16* __restrict__ h1b,
                  float* __restrict__ dinv) {
    __shared__ float w1s[IN_DIM * HID_DIM];  // 32 KB
    __shared__ float xs[16][IN_DIM];         // 8 KB
    int tid = threadIdx.x;
    const float4* W4 = (const float4*)W1;
    float4* w1s4 = (float4*)w1s;
#pragma unroll
    for (int i = 0; i < 8; ++i) w1s4[tid + 256 * i] = W4[tid + 256 * i];
    int wl = tid >> 6;
    int lane = tid & 63;
    int node0 = blockIdx.x * 16 + wl * 4;
    // wave loads its 4 x-rows: 128 float4s, 2 per lane
#pragma unroll
    for (int i = 0; i < 2; ++i) {
        int idx = lane + 64 * i;     // 0..127
        int r = idx >> 5;            // 32 float4 per row
        int c = idx & 31;
        ((float4*)xs[wl * 4 + r])[c] = ((const float4*)(x + (long)(node0 + r) * IN_DIM))[c];
    }
    __syncthreads();
    float acc[4] = {0.f, 0.f, 0.f, 0.f};
#pragma unroll 4
    for (int k = 0; k < IN_DIM; k += 4) {
        float4 xv0 = *(const float4*)&xs[wl * 4 + 0][k];
        float4 xv1 = *(const float4*)&xs[wl * 4 + 1][k];
        float4 xv2 = *(const float4*)&xs[wl * 4 + 2][k];
        float4 xv3 = *(const float4*)&xs[wl * 4 + 3][k];
        float w0 = w1s[(k + 0) * HID_DIM + lane];
        float w1 = w1s[(k + 1) * HID_DIM + lane];
        float w2 = w1s[(k + 2) * HID_DIM + lane];
        float w3 = w1s[(k + 3) * HID_DIM + lane];
        acc[0] += xv0.x * w0 + xv0.y * w1 + xv0.z * w2 + xv0.w * w3;
        acc[1] += xv1.x * w0 + xv1.y * w1 + xv1.z * w2 + xv1.w * w3;
        acc[2] += xv2.x * w0 + xv2.y * w1 + xv2.z * w2 + xv2.w * w3;
        acc[3] += xv3.x * w0 + xv3.y * w1 + xv3.z * w2 + xv3.w * w3;
    }
#pragma unroll
    for (int r = 0; r < 4; ++r) {
        float di = rsqrtf(degf[node0 + r]);
        h1b[(node0 + r) * HID_DIM + lane] = __float2bfloat16(acc[r] * di);
    }
    if (lane < 4) dinv[node0 + lane] = rsqrtf(degf[node0 + lane]);
}

// ---------------- fused: segmented gather L1 + finalize + relu + W2 GEMV ------
// wave per node, lane = column; edge metadata staged via LDS broadcast.
__global__ void gather1_layer2_kernel(const int* __restrict__ start, const int2* __restrict__ edge_s,
                                      const __hip_bfloat16* __restrict__ h1b,
                                      const float* __restrict__ dinv, const float* __restrict__ b1,
                                      const float* __restrict__ W2, float* __restrict__ h2s) {
    __shared__ int2 meta[4][64];
    int wave = (blockIdx.x * blockDim.x + threadIdx.x) >> 6;
    int wl = threadIdx.x >> 6;
    int lane = threadIdx.x & 63;
    if (wave >= N_NODES) return;
    int s0 = start[wave], s1 = start[wave + 1];
    float acc0 = 0.f, acc1 = 0.f, acc2 = 0.f, acc3 = 0.f;
    for (int base = s0; base < s1; base += 64) {
        int cnt = s1 - base;
        if (cnt > 64) cnt = 64;
        if (lane < cnt) meta[wl][lane] = edge_s[base + lane];
        __builtin_amdgcn_wave_barrier();
        int j = 0;
        for (; j + 4 <= cnt; j += 4) {
            int2 m0 = meta[wl][j + 0];
            int2 m1 = meta[wl][j + 1];
            int2 m2 = meta[wl][j + 2];
            int2 m3 = meta[wl][j + 3];
            float v0 = __bfloat162float(h1b[m0.x * HID_DIM + lane]);
            float v1 = __bfloat162float(h1b[m1.x * HID_DIM + lane]);
            float v2 = __bfloat162float(h1b[m2.x * HID_DIM + lane]);
            float v3 = __bfloat162float(h1b[m3.x * HID_DIM + lane]);
            acc0 += __int_as_float(m0.y) * v0;
            acc1 += __int_as_float(m1.y) * v1;
            acc2 += __int_as_float(m2.y) * v2;
            acc3 += __int_as_float(m3.y) * v3;
        }
        for (; j < cnt; ++j) {
            int2 m = meta[wl][j];
            acc0 += __int_as_float(m.y) * __bfloat162float(h1b[m.x * HID_DIM + lane]);
        }
        __builtin_amdgcn_wave_barrier();
    }
    float di = dinv[wave];
    float self = __bfloat162float(h1b[wave * HID_DIM + lane]);
    float z = di * (acc0 + acc1 + acc2 + acc3 + self) + b1[lane];
    float h = fmaxf(z, 0.0f);
    float v = h * W2[lane];
#pragma unroll
    for (int off = 32; off > 0; off >>= 1)
        v += __shfl_down(v, off, 64);
    if (lane == 0) h2s[wave] = v * di;
}

// ---------------- fused: segmented gather L2 + sigmoid ------------------------
__global__ void gather2_final_kernel(const int* __restrict__ start, const int2* __restrict__ edge_s,
                                     const float* __restrict__ h2s, const float* __restrict__ dinv,
                                     const float* __restrict__ b2, float* __restrict__ out) {
    int n = blockIdx.x * blockDim.x + threadIdx.x;
    if (n >= N_NODES) return;
    int s0 = start[n], s1 = start[n + 1];
    float acc = 0.0f;
    for (int t = s0; t < s1; ++t) {
        int2 m = edge_s[t];
        acc += __int_as_float(m.y) * h2s[m.x];
    }
    float z = dinv[n] * (acc + h2s[n]) + b2[0];
    out[n] = 1.0f / (1.0f + expf(-z));
}

extern "C" void kernel_launch(void* const* d_in, const int* in_sizes, int n_in,
                              void* d_out, int out_size, void* d_ws, size_t ws_size,
                              hipStream_t stream) {
    const float* x  = (const float*)d_in[0];
    const int*   ei = (const int*)d_in[1];
    const float* ew = (const float*)d_in[2];
    const float* W1 = (const float*)d_in[3];
    const float* b1 = (const float*)d_in[4];
    const float* W2 = (const float*)d_in[5];
    const float* b2 = (const float*)d_in[6];
    float* out = (float*)d_out;

    const int* src = ei;
    const int* dst = ei + N_EDGES;

    // workspace layout (edge_s first for 8B alignment)
    char* ws = (char*)d_ws;
    int2*  edge_s = (int2*)ws;               ws += (size_t)N_EDGES * sizeof(int2);
    int*   start  = (int*)ws;                ws += (N_NODES + 1) * sizeof(int);
    int*   counts = (int*)ws;                ws += N_NODES * sizeof(int);
    int*   cursor = (int*)ws;                ws += N_NODES * sizeof(int);
    float* degf   = (float*)ws;              ws += N_NODES * sizeof(float);
    int*   bsum   = (int*)ws;                ws += SCAN_B * sizeof(int);
    int*   boff   = (int*)ws;                ws += SCAN_B * sizeof(int);
    float* dinv   = (float*)ws;              ws += N_NODES * sizeof(float);
    float* h2s    = (float*)ws;              ws += N_NODES * sizeof(float);
    __hip_bfloat16* h1b = (__hip_bfloat16*)ws;  // N_NODES * HID_DIM bf16

    const int B = 256;
    const int nbN = (N_NODES + B - 1) / B;
    const int nbE = (N_EDGES + B - 1) / B;

    init_kernel<<<nbN, B, 0, stream>>>(counts, cursor, degf, start);
    hist_kernel<<<nbE, B, 0, stream>>>(dst, ew, counts, degf);
    scan1_kernel<<<SCAN_NB, SCAN_B, 0, stream>>>(counts, start, bsum);
    scan2_kernel<<<1, SCAN_B, 0, stream>>>(bsum, boff);
    scan3_kernel<<<SCAN_NB, SCAN_B, 0, stream>>>(start, boff);
    sort_kernel<<<nbE, B, 0, stream>>>(src, dst, ew, start, cursor, edge_s);
    gemm1_kernel<<<N_NODES / 16, 256, 0, stream>>>(x, W1, degf, h1b, dinv);
    gather1_layer2_kernel<<<(N_NODES * 64) / B, B, 0, stream>>>(start, edge_s, h1b, dinv, b1, W2, h2s);
    gather2_final_kernel<<<nbN, B, 0, stream>>>(start, edge_s, h2s, dinv, b2, out);
}

// Round 4
// 205.838 us; speedup vs baseline: 2.1771x; 1.3037x over previous
//
#include <hip/hip_runtime.h>
#include <hip/hip_bf16.h>
#include <math.h>

#define N_NODES 50000
#define N_EDGES 800000
#define IN_DIM  128
#define HID_DIM 64

#define SCAN_B   256
#define SCAN_NB  ((N_NODES + SCAN_B - 1) / SCAN_B)   // 196

// ---------------- init: zero counts, start[0]=0 -------------------------------
__global__ void init_kernel(int* __restrict__ counts, int* __restrict__ start) {
    int i = blockIdx.x * blockDim.x + threadIdx.x;
    if (i < N_NODES) counts[i] = 0;
    if (i == 0) start[0] = 0;
}

// ---------------- histogram of dst; atomic return value = within-bucket rank --
__global__ void hist_kernel(const int* __restrict__ dst, int* __restrict__ counts,
                            unsigned short* __restrict__ rank) {
    int e = blockIdx.x * blockDim.x + threadIdx.x;
    if (e < N_EDGES) {
        int r = atomicAdd(&counts[dst[e]], 1);
        rank[e] = (unsigned short)r;
    }
}

// ---------------- scan step 1: per-block inclusive scan -----------------------
__global__ void scan1_kernel(const int* __restrict__ counts, int* __restrict__ start,
                             int* __restrict__ bsum) {
    __shared__ int s[SCAN_B];
    int tid = threadIdx.x;
    int i = blockIdx.x * SCAN_B + tid;
    int v = (i < N_NODES) ? counts[i] : 0;
    s[tid] = v;
    __syncthreads();
#pragma unroll
    for (int off = 1; off < SCAN_B; off <<= 1) {
        int t = (tid >= off) ? s[tid - off] : 0;
        __syncthreads();
        s[tid] += t;
        __syncthreads();
    }
    if (i < N_NODES) start[i + 1] = s[tid];
    if (tid == SCAN_B - 1) bsum[blockIdx.x] = s[tid];
}

// ---------------- scan step 2: exclusive scan of block sums -------------------
__global__ void scan2_kernel(const int* __restrict__ bsum, int* __restrict__ boff) {
    __shared__ int s[SCAN_B];
    int tid = threadIdx.x;
    int v = (tid < SCAN_NB) ? bsum[tid] : 0;
    s[tid] = v;
    __syncthreads();
#pragma unroll
    for (int off = 1; off < SCAN_B; off <<= 1) {
        int t = (tid >= off) ? s[tid - off] : 0;
        __syncthreads();
        s[tid] += t;
        __syncthreads();
    }
    if (tid < SCAN_NB) boff[tid] = s[tid] - v;
}

// ---------------- scan step 3: add block offsets ------------------------------
__global__ void scan3_kernel(int* __restrict__ start, const int* __restrict__ boff) {
    int i = blockIdx.x * SCAN_B + threadIdx.x;
    if (i < N_NODES) start[i + 1] += boff[blockIdx.x];
}

// ---------------- scatter edges into dst-sorted packed array (NO atomics) -----
__global__ void sort_kernel(const int* __restrict__ src, const int* __restrict__ dst,
                            const float* __restrict__ ew, const int* __restrict__ start,
                            const unsigned short* __restrict__ rank,
                            int2* __restrict__ edge_s) {
    int e = blockIdx.x * blockDim.x + threadIdx.x;
    if (e >= N_EDGES) return;
    int d = dst[e];
    int pos = start[d] + (int)rank[e];
    edge_s[pos] = make_int2(src[e], __float_as_int(ew[e]));
}

// ---------------- dinv from sorted segments: rsqrt(1 + sum(ew)) ---------------
__global__ void degdinv_kernel(const int* __restrict__ start, const int2* __restrict__ edge_s,
                               float* __restrict__ dinv) {
    int n = blockIdx.x * blockDim.x + threadIdx.x;
    if (n >= N_NODES) return;
    int s0 = start[n], s1 = start[n + 1];
    float deg = 1.0f;                                  // self-loop weight
    for (int t = s0; t < s1; ++t) deg += __int_as_float(edge_s[t].y);
    dinv[n] = rsqrtf(deg);
}

// ---------------- h1b = bf16((x @ W1) * dinv) ---------------------------------
// 16 nodes/block, 4 nodes/wave: W1 in LDS amortized, 4 FMAs per LDS w-read.
// 50000 = 3125 * 16 exactly, so no bounds checks needed.
__global__ __launch_bounds__(256)
void gemm1_kernel(const float* __restrict__ x, const float* __restrict__ W1,
                  const float* __restrict__ dinv, __hip_bfloat16* __restrict__ h1b) {
    __shared__ float w1s[IN_DIM * HID_DIM];  // 32 KB
    __shared__ float xs[16][IN_DIM];         // 8 KB
    int tid = threadIdx.x;
    const float4* W4 = (const float4*)W1;
    float4* w1s4 = (float4*)w1s;
#pragma unroll
    for (int i = 0; i < 8; ++i) w1s4[tid + 256 * i] = W4[tid + 256 * i];
    int wl = tid >> 6;
    int lane = tid & 63;
    int node0 = blockIdx.x * 16 + wl * 4;
#pragma unroll
    for (int i = 0; i < 2; ++i) {
        int idx = lane + 64 * i;     // 0..127
        int r = idx >> 5;            // 32 float4 per row
        int c = idx & 31;
        ((float4*)xs[wl * 4 + r])[c] = ((const float4*)(x + (long)(node0 + r) * IN_DIM))[c];
    }
    __syncthreads();
    float acc[4] = {0.f, 0.f, 0.f, 0.f};
#pragma unroll 4
    for (int k = 0; k < IN_DIM; k += 4) {
        float4 xv0 = *(const float4*)&xs[wl * 4 + 0][k];
        float4 xv1 = *(const float4*)&xs[wl * 4 + 1][k];
        float4 xv2 = *(const float4*)&xs[wl * 4 + 2][k];
        float4 xv3 = *(const float4*)&xs[wl * 4 + 3][k];
        float w0 = w1s[(k + 0) * HID_DIM + lane];
        float w1 = w1s[(k + 1) * HID_DIM + lane];
        float w2 = w1s[(k + 2) * HID_DIM + lane];
        float w3 = w1s[(k + 3) * HID_DIM + lane];
        acc[0] += xv0.x * w0 + xv0.y * w1 + xv0.z * w2 + xv0.w * w3;
        acc[1] += xv1.x * w0 + xv1.y * w1 + xv1.z * w2 + xv1.w * w3;
        acc[2] += xv2.x * w0 + xv2.y * w1 + xv2.z * w2 + xv2.w * w3;
        acc[3] += xv3.x * w0 + xv3.y * w1 + xv3.z * w2 + xv3.w * w3;
    }
#pragma unroll
    for (int r = 0; r < 4; ++r)
        h1b[(node0 + r) * HID_DIM + lane] = __float2bfloat16(acc[r] * dinv[node0 + r]);
}

// ---------------- fused: segmented gather L1 + finalize + relu + W2 GEMV ------
// wave per node, lane = column; edge metadata staged via LDS broadcast.
__global__ void gather1_layer2_kernel(const int* __restrict__ start, const int2* __restrict__ edge_s,
                                      const __hip_bfloat16* __restrict__ h1b,
                                      const float* __restrict__ dinv, const float* __restrict__ b1,
                                      const float* __restrict__ W2, float* __restrict__ h2s) {
    __shared__ int2 meta[4][64];
    int wave = (blockIdx.x * blockDim.x + threadIdx.x) >> 6;
    int wl = threadIdx.x >> 6;
    int lane = threadIdx.x & 63;
    if (wave >= N_NODES) return;
    int s0 = start[wave], s1 = start[wave + 1];
    float acc0 = 0.f, acc1 = 0.f, acc2 = 0.f, acc3 = 0.f;
    for (int base = s0; base < s1; base += 64) {
        int cnt = s1 - base;
        if (cnt > 64) cnt = 64;
        if (lane < cnt) meta[wl][lane] = edge_s[base + lane];
        __builtin_amdgcn_wave_barrier();
        int j = 0;
        for (; j + 8 <= cnt; j += 8) {
            int2 m0 = meta[wl][j + 0];
            int2 m1 = meta[wl][j + 1];
            int2 m2 = meta[wl][j + 2];
            int2 m3 = meta[wl][j + 3];
            int2 m4 = meta[wl][j + 4];
            int2 m5 = meta[wl][j + 5];
            int2 m6 = meta[wl][j + 6];
            int2 m7 = meta[wl][j + 7];
            float v0 = __bfloat162float(h1b[m0.x * HID_DIM + lane]);
            float v1 = __bfloat162float(h1b[m1.x * HID_DIM + lane]);
            float v2 = __bfloat162float(h1b[m2.x * HID_DIM + lane]);
            float v3 = __bfloat162float(h1b[m3.x * HID_DIM + lane]);
            float v4 = __bfloat162float(h1b[m4.x * HID_DIM + lane]);
            float v5 = __bfloat162float(h1b[m5.x * HID_DIM + lane]);
            float v6 = __bfloat162float(h1b[m6.x * HID_DIM + lane]);
            float v7 = __bfloat162float(h1b[m7.x * HID_DIM + lane]);
            acc0 += __int_as_float(m0.y) * v0;
            acc1 += __int_as_float(m1.y) * v1;
            acc2 += __int_as_float(m2.y) * v2;
            acc3 += __int_as_float(m3.y) * v3;
            acc0 += __int_as_float(m4.y) * v4;
            acc1 += __int_as_float(m5.y) * v5;
            acc2 += __int_as_float(m6.y) * v6;
            acc3 += __int_as_float(m7.y) * v7;
        }
        for (; j + 2 <= cnt; j += 2) {
            int2 m0 = meta[wl][j + 0];
            int2 m1 = meta[wl][j + 1];
            float v0 = __bfloat162float(h1b[m0.x * HID_DIM + lane]);
            float v1 = __bfloat162float(h1b[m1.x * HID_DIM + lane]);
            acc0 += __int_as_float(m0.y) * v0;
            acc1 += __int_as_float(m1.y) * v1;
        }
        if (j < cnt) {
            int2 m = meta[wl][j];
            acc0 += __int_as_float(m.y) * __bfloat162float(h1b[m.x * HID_DIM + lane]);
        }
        __builtin_amdgcn_wave_barrier();
    }
    float di = dinv[wave];
    float self = __bfloat162float(h1b[wave * HID_DIM + lane]);
    float z = di * (acc0 + acc1 + acc2 + acc3 + self) + b1[lane];
    float h = fmaxf(z, 0.0f);
    float v = h * W2[lane];
#pragma unroll
    for (int off = 32; off > 0; off >>= 1)
        v += __shfl_down(v, off, 64);
    if (lane == 0) h2s[wave] = v * di;
}

// ---------------- fused: segmented gather L2 + sigmoid ------------------------
__global__ void gather2_final_kernel(const int* __restrict__ start, const int2* __restrict__ edge_s,
                                     const float* __restrict__ h2s, const float* __restrict__ dinv,
                                     const float* __restrict__ b2, float* __restrict__ out) {
    int n = blockIdx.x * blockDim.x + threadIdx.x;
    if (n >= N_NODES) return;
    int s0 = start[n], s1 = start[n + 1];
    float acc = 0.0f;
    for (int t = s0; t < s1; ++t) {
        int2 m = edge_s[t];
        acc += __int_as_float(m.y) * h2s[m.x];
    }
    float z = dinv[n] * (acc + h2s[n]) + b2[0];
    out[n] = 1.0f / (1.0f + expf(-z));
}

extern "C" void kernel_launch(void* const* d_in, const int* in_sizes, int n_in,
                              void* d_out, int out_size, void* d_ws, size_t ws_size,
                              hipStream_t stream) {
    const float* x  = (const float*)d_in[0];
    const int*   ei = (const int*)d_in[1];
    const float* ew = (const float*)d_in[2];
    const float* W1 = (const float*)d_in[3];
    const float* b1 = (const float*)d_in[4];
    const float* W2 = (const float*)d_in[5];
    const float* b2 = (const float*)d_in[6];
    float* out = (float*)d_out;

    const int* src = ei;
    const int* dst = ei + N_EDGES;

    // workspace layout (edge_s first for 8B alignment)
    char* ws = (char*)d_ws;
    int2*  edge_s = (int2*)ws;               ws += (size_t)N_EDGES * sizeof(int2);
    int*   start  = (int*)ws;                ws += (N_NODES + 1) * sizeof(int);
    int*   counts = (int*)ws;                ws += N_NODES * sizeof(int);
    unsigned short* rank = (unsigned short*)ws; ws += (size_t)N_EDGES * sizeof(unsigned short);
    int*   bsum   = (int*)ws;                ws += SCAN_B * sizeof(int);
    int*   boff   = (int*)ws;                ws += SCAN_B * sizeof(int);
    float* dinv   = (float*)ws;              ws += N_NODES * sizeof(float);
    float* h2s    = (float*)ws;              ws += N_NODES * sizeof(float);
    __hip_bfloat16* h1b = (__hip_bfloat16*)ws;  // N_NODES * HID_DIM bf16

    const int B = 256;
    const int nbN = (N_NODES + B - 1) / B;
    const int nbE = (N_EDGES + B - 1) / B;

    init_kernel<<<nbN, B, 0, stream>>>(counts, start);
    hist_kernel<<<nbE, B, 0, stream>>>(dst, counts, rank);
    scan1_kernel<<<SCAN_NB, SCAN_B, 0, stream>>>(counts, start, bsum);
    scan2_kernel<<<1, SCAN_B, 0, stream>>>(bsum, boff);
    scan3_kernel<<<SCAN_NB, SCAN_B, 0, stream>>>(start, boff);
    sort_kernel<<<nbE, B, 0, stream>>>(src, dst, ew, start, rank, edge_s);
    degdinv_kernel<<<nbN, B, 0, stream>>>(start, edge_s, dinv);
    gemm1_kernel<<<N_NODES / 16, 256, 0, stream>>>(x, W1, dinv, h1b);
    gather1_layer2_kernel<<<(N_NODES * 64) / B, B, 0, stream>>>(start, edge_s, h1b, dinv, b1, W2, h2s);
    gather2_final_kernel<<<nbN, B, 0, stream>>>(start, edge_s, h2s, dinv, b2, out);
}

// Round 5
// 191.695 us; speedup vs baseline: 2.3377x; 1.0738x over previous
//
#include <hip/hip_runtime.h>
#include <hip/hip_bf16.h>
#include <math.h>

#define N_NODES 50000
#define N_EDGES 800000
#define IN_DIM  128
#define HID_DIM 64

#define SCAN_B   256
#define SCAN_NB  ((N_NODES + SCAN_B - 1) / SCAN_B)   // 196

// ---------------- init: zero counts, start[0]=0 -------------------------------
__global__ void init_kernel(int* __restrict__ counts, int* __restrict__ start) {
    int i = blockIdx.x * blockDim.x + threadIdx.x;
    if (i < N_NODES) counts[i] = 0;
    if (i == 0) start[0] = 0;
}

// ---------------- fused: hist (odd blocks) + gemm1 (even blocks) --------------
// hist: atomic rank build, memory-op-latency bound, ~0% VALU.
// gemm: h1b = bf16(x @ W1), UNSCALED (dinv applied later in gather1).
// Interleaved by block parity so each CU co-schedules both kinds — gemm's
// VALU work hides under hist's atomic latency.
// 800000 = 3125*256 and 50000 = 3125*16 exactly: no bounds checks.
__global__ __launch_bounds__(256)
void histgemm_kernel(const int* __restrict__ dst, int* __restrict__ counts,
                     unsigned short* __restrict__ rank,
                     const float* __restrict__ x, const float* __restrict__ W1,
                     __hip_bfloat16* __restrict__ h1b) {
    __shared__ float w1s[IN_DIM * HID_DIM];  // 32 KB
    __shared__ float xs[16][IN_DIM];         // 8 KB
    int bid = blockIdx.x;
    int tid = threadIdx.x;
    if (bid & 1) {
        // ---- hist path ----
        int e = (bid >> 1) * 256 + tid;
        int r = atomicAdd(&counts[dst[e]], 1);
        rank[e] = (unsigned short)r;
        return;
    }
    // ---- gemm path ----
    int gb = bid >> 1;                       // 0..3124
    const float4* W4 = (const float4*)W1;
    float4* w1s4 = (float4*)w1s;
#pragma unroll
    for (int i = 0; i < 8; ++i) w1s4[tid + 256 * i] = W4[tid + 256 * i];
    int wl = tid >> 6;
    int lane = tid & 63;
    int node0 = gb * 16 + wl * 4;
#pragma unroll
    for (int i = 0; i < 2; ++i) {
        int idx = lane + 64 * i;             // 0..127
        int r = idx >> 5;                    // 32 float4 per row
        int c = idx & 31;
        ((float4*)xs[wl * 4 + r])[c] = ((const float4*)(x + (long)(node0 + r) * IN_DIM))[c];
    }
    __syncthreads();
    float acc[4] = {0.f, 0.f, 0.f, 0.f};
#pragma unroll 4
    for (int k = 0; k < IN_DIM; k += 4) {
        float4 xv0 = *(const float4*)&xs[wl * 4 + 0][k];
        float4 xv1 = *(const float4*)&xs[wl * 4 + 1][k];
        float4 xv2 = *(const float4*)&xs[wl * 4 + 2][k];
        float4 xv3 = *(const float4*)&xs[wl * 4 + 3][k];
        float w0 = w1s[(k + 0) * HID_DIM + lane];
        float w1 = w1s[(k + 1) * HID_DIM + lane];
        float w2 = w1s[(k + 2) * HID_DIM + lane];
        float w3 = w1s[(k + 3) * HID_DIM + lane];
        acc[0] += xv0.x * w0 + xv0.y * w1 + xv0.z * w2 + xv0.w * w3;
        acc[1] += xv1.x * w0 + xv1.y * w1 + xv1.z * w2 + xv1.w * w3;
        acc[2] += xv2.x * w0 + xv2.y * w1 + xv2.z * w2 + xv2.w * w3;
        acc[3] += xv3.x * w0 + xv3.y * w1 + xv3.z * w2 + xv3.w * w3;
    }
#pragma unroll
    for (int r = 0; r < 4; ++r)
        h1b[(node0 + r) * HID_DIM + lane] = __float2bfloat16(acc[r]);
}

// ---------------- scan step 1: per-block inclusive scan -----------------------
__global__ void scan1_kernel(const int* __restrict__ counts, int* __restrict__ start,
                             int* __restrict__ bsum) {
    __shared__ int s[SCAN_B];
    int tid = threadIdx.x;
    int i = blockIdx.x * SCAN_B + tid;
    int v = (i < N_NODES) ? counts[i] : 0;
    s[tid] = v;
    __syncthreads();
#pragma unroll
    for (int off = 1; off < SCAN_B; off <<= 1) {
        int t = (tid >= off) ? s[tid - off] : 0;
        __syncthreads();
        s[tid] += t;
        __syncthreads();
    }
    if (i < N_NODES) start[i + 1] = s[tid];
    if (tid == SCAN_B - 1) bsum[blockIdx.x] = s[tid];
}

// ---------------- scan step 2: exclusive scan of block sums -------------------
__global__ void scan2_kernel(const int* __restrict__ bsum, int* __restrict__ boff) {
    __shared__ int s[SCAN_B];
    int tid = threadIdx.x;
    int v = (tid < SCAN_NB) ? bsum[tid] : 0;
    s[tid] = v;
    __syncthreads();
#pragma unroll
    for (int off = 1; off < SCAN_B; off <<= 1) {
        int t = (tid >= off) ? s[tid - off] : 0;
        __syncthreads();
        s[tid] += t;
        __syncthreads();
    }
    if (tid < SCAN_NB) boff[tid] = s[tid] - v;
}

// ---------------- scan step 3: add block offsets ------------------------------
__global__ void scan3_kernel(int* __restrict__ start, const int* __restrict__ boff) {
    int i = blockIdx.x * SCAN_B + threadIdx.x;
    if (i < N_NODES) start[i + 1] += boff[blockIdx.x];
}

// ---------------- scatter edges into dst-sorted packed array (NO atomics) -----
__global__ void sort_kernel(const int* __restrict__ src, const int* __restrict__ dst,
                            const float* __restrict__ ew, const int* __restrict__ start,
                            const unsigned short* __restrict__ rank,
                            int2* __restrict__ edge_s) {
    int e = blockIdx.x * blockDim.x + threadIdx.x;
    if (e >= N_EDGES) return;
    int d = dst[e];
    int pos = start[d] + (int)rank[e];
    edge_s[pos] = make_int2(src[e], __float_as_int(ew[e]));
}

// ---------------- dinv from sorted segments: rsqrt(1 + sum(ew)) ---------------
__global__ void degdinv_kernel(const int* __restrict__ start, const int2* __restrict__ edge_s,
                               float* __restrict__ dinv) {
    int n = blockIdx.x * blockDim.x + threadIdx.x;
    if (n >= N_NODES) return;
    int s0 = start[n], s1 = start[n + 1];
    float deg = 1.0f;                                  // self-loop weight
    for (int t = s0; t < s1; ++t) deg += __int_as_float(edge_s[t].y);
    dinv[n] = rsqrtf(deg);
}

// ---------------- fused: segmented gather L1 + finalize + relu + W2 GEMV ------
// wave per node, lane = column. dinv[src] is folded into the staged edge
// weight during the LDS staging phase (L2-resident 4B random load per edge).
__global__ void gather1_layer2_kernel(const int* __restrict__ start, const int2* __restrict__ edge_s,
                                      const __hip_bfloat16* __restrict__ h1b,
                                      const float* __restrict__ dinv, const float* __restrict__ b1,
                                      const float* __restrict__ W2, float* __restrict__ h2s) {
    __shared__ int2 meta[4][64];
    int wave = (blockIdx.x * blockDim.x + threadIdx.x) >> 6;
    int wl = threadIdx.x >> 6;
    int lane = threadIdx.x & 63;
    if (wave >= N_NODES) return;
    int s0 = start[wave], s1 = start[wave + 1];
    float acc0 = 0.f, acc1 = 0.f, acc2 = 0.f, acc3 = 0.f;
    for (int base = s0; base < s1; base += 64) {
        int cnt = s1 - base;
        if (cnt > 64) cnt = 64;
        if (lane < cnt) {
            int2 m = edge_s[base + lane];
            float w = __int_as_float(m.y) * dinv[m.x];   // fold dinv[src] here
            meta[wl][lane] = make_int2(m.x, __float_as_int(w));
        }
        __builtin_amdgcn_wave_barrier();
        int j = 0;
        for (; j + 8 <= cnt; j += 8) {
            int2 m0 = meta[wl][j + 0];
            int2 m1 = meta[wl][j + 1];
            int2 m2 = meta[wl][j + 2];
            int2 m3 = meta[wl][j + 3];
            int2 m4 = meta[wl][j + 4];
            int2 m5 = meta[wl][j + 5];
            int2 m6 = meta[wl][j + 6];
            int2 m7 = meta[wl][j + 7];
            float v0 = __bfloat162float(h1b[m0.x * HID_DIM + lane]);
            float v1 = __bfloat162float(h1b[m1.x * HID_DIM + lane]);
            float v2 = __bfloat162float(h1b[m2.x * HID_DIM + lane]);
            float v3 = __bfloat162float(h1b[m3.x * HID_DIM + lane]);
            float v4 = __bfloat162float(h1b[m4.x * HID_DIM + lane]);
            float v5 = __bfloat162float(h1b[m5.x * HID_DIM + lane]);
            float v6 = __bfloat162float(h1b[m6.x * HID_DIM + lane]);
            float v7 = __bfloat162float(h1b[m7.x * HID_DIM + lane]);
            acc0 += __int_as_float(m0.y) * v0;
            acc1 += __int_as_float(m1.y) * v1;
            acc2 += __int_as_float(m2.y) * v2;
            acc3 += __int_as_float(m3.y) * v3;
            acc0 += __int_as_float(m4.y) * v4;
            acc1 += __int_as_float(m5.y) * v5;
            acc2 += __int_as_float(m6.y) * v6;
            acc3 += __int_as_float(m7.y) * v7;
        }
        for (; j + 2 <= cnt; j += 2) {
            int2 m0 = meta[wl][j + 0];
            int2 m1 = meta[wl][j + 1];
            float v0 = __bfloat162float(h1b[m0.x * HID_DIM + lane]);
            float v1 = __bfloat162float(h1b[m1.x * HID_DIM + lane]);
            acc0 += __int_as_float(m0.y) * v0;
            acc1 += __int_as_float(m1.y) * v1;
        }
        if (j < cnt) {
            int2 m = meta[wl][j];
            acc0 += __int_as_float(m.y) * __bfloat162float(h1b[m.x * HID_DIM + lane]);
        }
        __builtin_amdgcn_wave_barrier();
    }
    float di = dinv[wave];
    float self = __bfloat162float(h1b[wave * HID_DIM + lane]);   // unscaled
    float z = di * (acc0 + acc1 + acc2 + acc3 + di * self) + b1[lane];
    float h = fmaxf(z, 0.0f);
    float v = h * W2[lane];
#pragma unroll
    for (int off = 32; off > 0; off >>= 1)
        v += __shfl_down(v, off, 64);
    if (lane == 0) h2s[wave] = v * di;
}

// ---------------- fused: segmented gather L2 + sigmoid ------------------------
__global__ void gather2_final_kernel(const int* __restrict__ start, const int2* __restrict__ edge_s,
                                     const float* __restrict__ h2s, const float* __restrict__ dinv,
                                     const float* __restrict__ b2, float* __restrict__ out) {
    int n = blockIdx.x * blockDim.x + threadIdx.x;
    if (n >= N_NODES) return;
    int s0 = start[n], s1 = start[n + 1];
    float acc = 0.0f;
    for (int t = s0; t < s1; ++t) {
        int2 m = edge_s[t];
        acc += __int_as_float(m.y) * h2s[m.x];
    }
    float z = dinv[n] * (acc + h2s[n]) + b2[0];
    out[n] = 1.0f / (1.0f + expf(-z));
}

extern "C" void kernel_launch(void* const* d_in, const int* in_sizes, int n_in,
                              void* d_out, int out_size, void* d_ws, size_t ws_size,
                              hipStream_t stream) {
    const float* x  = (const float*)d_in[0];
    const int*   ei = (const int*)d_in[1];
    const float* ew = (const float*)d_in[2];
    const float* W1 = (const float*)d_in[3];
    const float* b1 = (const float*)d_in[4];
    const float* W2 = (const float*)d_in[5];
    const float* b2 = (const float*)d_in[6];
    float* out = (float*)d_out;

    const int* src = ei;
    const int* dst = ei + N_EDGES;

    // workspace layout (edge_s first for 8B alignment)
    char* ws = (char*)d_ws;
    int2*  edge_s = (int2*)ws;               ws += (size_t)N_EDGES * sizeof(int2);
    int*   start  = (int*)ws;                ws += (N_NODES + 1) * sizeof(int);
    int*   counts = (int*)ws;                ws += N_NODES * sizeof(int);
    unsigned short* rank = (unsigned short*)ws; ws += (size_t)N_EDGES * sizeof(unsigned short);
    int*   bsum   = (int*)ws;                ws += SCAN_B * sizeof(int);
    int*   boff   = (int*)ws;                ws += SCAN_B * sizeof(int);
    float* dinv   = (float*)ws;              ws += N_NODES * sizeof(float);
    float* h2s    = (float*)ws;              ws += N_NODES * sizeof(float);
    __hip_bfloat16* h1b = (__hip_bfloat16*)ws;  // N_NODES * HID_DIM bf16

    const int B = 256;
    const int nbN = (N_NODES + B - 1) / B;
    const int nbE = (N_EDGES + B - 1) / B;

    init_kernel<<<nbN, B, 0, stream>>>(counts, start);
    histgemm_kernel<<<6250, B, 0, stream>>>(dst, counts, rank, x, W1, h1b);
    scan1_kernel<<<SCAN_NB, SCAN_B, 0, stream>>>(counts, start, bsum);
    scan2_kernel<<<1, SCAN_B, 0, stream>>>(bsum, boff);
    scan3_kernel<<<SCAN_NB, SCAN_B, 0, stream>>>(start, boff);
    sort_kernel<<<nbE, B, 0, stream>>>(src, dst, ew, start, rank, edge_s);
    degdinv_kernel<<<nbN, B, 0, stream>>>(start, edge_s, dinv);
    gather1_layer2_kernel<<<(N_NODES * 64) / B, B, 0, stream>>>(start, edge_s, h1b, dinv, b1, W2, h2s);
    gather2_final_kernel<<<nbN, B, 0, stream>>>(start, edge_s, h2s, dinv, b2, out);
}

// Round 6
// 162.564 us; speedup vs baseline: 2.7566x; 1.1792x over previous
//
#include <hip/hip_runtime.h>
#include <hip/hip_bf16.h>
#include <math.h>

#define N_NODES 50000
#define N_EDGES 800000
#define IN_DIM  128
#define HID_DIM 64

#define NBKT     196        // buckets of 256 nodes: bucket = node >> 8
#define BKT_CAP  5000       // mean 4092, sd 64 -> +14 sigma, safe
#define NPASSC   200        // partition blocks, 4000 edges each
#define EDGES_PER_PASSC (N_EDGES / NPASSC)   // 4000
#define NGEMM    3125       // 50000 / 16 nodes per block

// =============== kernel 1: fused bucket-partition (blocks 0..199) =============
// =============== + gemm h1b = bf16(x @ W1) (blocks 200..3324) =================
// PassC: LDS histogram over 196 buckets, ONE global atomic per (block,bucket)
// to reserve a contiguous run, then write packed edges (src | ldst<<16, ew)
// into fixed-capacity bucket regions. src < 65536 (16b), ldst < 256 (8b).
// gemm: proven R5 structure (W1 + x staged in LDS, 4 nodes/wave).
__global__ __launch_bounds__(256)
void partgemm_kernel(const int* __restrict__ src, const int* __restrict__ dst,
                     const float* __restrict__ ew, int* __restrict__ gcursor,
                     int2* __restrict__ edge_b,
                     const float* __restrict__ x, const float* __restrict__ W1,
                     __hip_bfloat16* __restrict__ h1b) {
    __shared__ float w1s[IN_DIM * HID_DIM];  // 32 KB (PassC overlays counters here)
    __shared__ float xs[16][IN_DIM];         // 8 KB
    int bid = blockIdx.x;
    int tid = threadIdx.x;
    if (bid < NPASSC) {
        // ---- PassC: partition into buckets ----
        int* cnt1    = (int*)w1s;            // [196]
        int* cnt2    = cnt1 + NBKT;          // [196]
        int* runbase = cnt2 + NBKT;          // [196]
        if (tid < NBKT) { cnt1[tid] = 0; cnt2[tid] = 0; }
        __syncthreads();
        int e0 = bid * EDGES_PER_PASSC;
        for (int i = tid; i < EDGES_PER_PASSC; i += 256)
            atomicAdd(&cnt1[dst[e0 + i] >> 8], 1);
        __syncthreads();
        if (tid < NBKT) {
            int c = cnt1[tid];
            runbase[tid] = (c > 0) ? atomicAdd(&gcursor[tid], c) : 0;
        }
        __syncthreads();
        for (int i = tid; i < EDGES_PER_PASSC; i += 256) {
            int e = e0 + i;
            int d = dst[e];
            int b = d >> 8;
            int lr = atomicAdd(&cnt2[b], 1);
            int pos = b * BKT_CAP + runbase[b] + lr;
            edge_b[pos] = make_int2(src[e] | ((d & 255) << 16), __float_as_int(ew[e]));
        }
        return;
    }
    // ---- gemm path ----
    int gb = bid - NPASSC;                   // 0..3124
    const float4* W4 = (const float4*)W1;
    float4* w1s4 = (float4*)w1s;
#pragma unroll
    for (int i = 0; i < 8; ++i) w1s4[tid + 256 * i] = W4[tid + 256 * i];
    int wl = tid >> 6;
    int lane = tid & 63;
    int node0 = gb * 16 + wl * 4;
#pragma unroll
    for (int i = 0; i < 2; ++i) {
        int idx = lane + 64 * i;             // 0..127
        int r = idx >> 5;                    // 32 float4 per row
        int c = idx & 31;
        ((float4*)xs[wl * 4 + r])[c] = ((const float4*)(x + (long)(node0 + r) * IN_DIM))[c];
    }
    __syncthreads();
    float acc[4] = {0.f, 0.f, 0.f, 0.f};
#pragma unroll 4
    for (int k = 0; k < IN_DIM; k += 4) {
        float4 xv0 = *(const float4*)&xs[wl * 4 + 0][k];
        float4 xv1 = *(const float4*)&xs[wl * 4 + 1][k];
        float4 xv2 = *(const float4*)&xs[wl * 4 + 2][k];
        float4 xv3 = *(const float4*)&xs[wl * 4 + 3][k];
        float w0 = w1s[(k + 0) * HID_DIM + lane];
        float w1 = w1s[(k + 1) * HID_DIM + lane];
        float w2 = w1s[(k + 2) * HID_DIM + lane];
        float w3 = w1s[(k + 3) * HID_DIM + lane];
        acc[0] += xv0.x * w0 + xv0.y * w1 + xv0.z * w2 + xv0.w * w3;
        acc[1] += xv1.x * w0 + xv1.y * w1 + xv1.z * w2 + xv1.w * w3;
        acc[2] += xv2.x * w0 + xv2.y * w1 + xv2.z * w2 + xv2.w * w3;
        acc[3] += xv3.x * w0 + xv3.y * w1 + xv3.z * w2 + xv3.w * w3;
    }
#pragma unroll
    for (int r = 0; r < 4; ++r)
        h1b[(node0 + r) * HID_DIM + lane] = __float2bfloat16(acc[r]);
}

// =============== kernel 2: per-bucket fine sort + start/cnt/dinv ==============
// One block per bucket. Per-node count/deg/scan in LDS (no global atomics),
// then scatter edges node-sorted into edge_s (same bucket-region layout).
__global__ __launch_bounds__(256)
void bsort_kernel(const int* __restrict__ gcursor, const int2* __restrict__ edge_b,
                  int2* __restrict__ edge_s, int* __restrict__ start_g,
                  int* __restrict__ cnt_g, float* __restrict__ dinv) {
    __shared__ int   cnt[256];
    __shared__ int   cnt2[256];
    __shared__ float deg[256];
    __shared__ int   sc[256];
    int b   = blockIdx.x;
    int tid = threadIdx.x;
    int M    = gcursor[b];
    int base = b * BKT_CAP;
    cnt[tid] = 0; cnt2[tid] = 0; deg[tid] = 0.0f;
    __syncthreads();
    for (int i = tid; i < M; i += 256) {
        int2 e = edge_b[base + i];
        int ld = (e.x >> 16) & 255;
        atomicAdd(&cnt[ld], 1);
        atomicAdd(&deg[ld], __int_as_float(e.y));
    }
    __syncthreads();
    // exclusive scan of cnt over 256 (Hillis-Steele inclusive, then shift)
    sc[tid] = cnt[tid];
    __syncthreads();
#pragma unroll
    for (int off = 1; off < 256; off <<= 1) {
        int t = (tid >= off) ? sc[tid - off] : 0;
        __syncthreads();
        sc[tid] += t;
        __syncthreads();
    }
    int startL = sc[tid] - cnt[tid];         // exclusive
    int node = b * 256 + tid;
    if (node < N_NODES) {
        start_g[node] = base + startL;
        cnt_g[node]   = cnt[tid];
        dinv[node]    = rsqrtf(1.0f + deg[tid]);
    }
    // stash exclusive offsets for the scatter phase
    sc[tid] = startL;
    __syncthreads();
    for (int i = tid; i < M; i += 256) {
        int2 e = edge_b[base + i];
        int ld = (e.x >> 16) & 255;
        int r = atomicAdd(&cnt2[ld], 1);
        edge_s[base + sc[ld] + r] = make_int2(e.x & 0xFFFF, e.y);
    }
}

// =============== kernel 3: gather L1 + finalize + relu + W2 GEMV ==============
// wave per node, lane = column; dinv[src] folded during LDS staging.
__global__ void gather1_layer2_kernel(const int* __restrict__ start_g, const int* __restrict__ cnt_g,
                                      const int2* __restrict__ edge_s,
                                      const __hip_bfloat16* __restrict__ h1b,
                                      const float* __restrict__ dinv, const float* __restrict__ b1,
                                      const float* __restrict__ W2, float* __restrict__ h2s) {
    __shared__ int2 meta[4][64];
    int wave = (blockIdx.x * blockDim.x + threadIdx.x) >> 6;
    int wl = threadIdx.x >> 6;
    int lane = threadIdx.x & 63;
    if (wave >= N_NODES) return;
    int s0 = start_g[wave];
    int ctotal = cnt_g[wave];
    float acc0 = 0.f, acc1 = 0.f, acc2 = 0.f, acc3 = 0.f;
    for (int done = 0; done < ctotal; done += 64) {
        int cnt = ctotal - done;
        if (cnt > 64) cnt = 64;
        if (lane < cnt) {
            int2 m = edge_s[s0 + done + lane];
            float w = __int_as_float(m.y) * dinv[m.x];   // fold dinv[src]
            meta[wl][lane] = make_int2(m.x, __float_as_int(w));
        }
        __builtin_amdgcn_wave_barrier();
        int j = 0;
        for (; j + 8 <= cnt; j += 8) {
            int2 m0 = meta[wl][j + 0];
            int2 m1 = meta[wl][j + 1];
            int2 m2 = meta[wl][j + 2];
            int2 m3 = meta[wl][j + 3];
            int2 m4 = meta[wl][j + 4];
            int2 m5 = meta[wl][j + 5];
            int2 m6 = meta[wl][j + 6];
            int2 m7 = meta[wl][j + 7];
            float v0 = __bfloat162float(h1b[m0.x * HID_DIM + lane]);
            float v1 = __bfloat162float(h1b[m1.x * HID_DIM + lane]);
            float v2 = __bfloat162float(h1b[m2.x * HID_DIM + lane]);
            float v3 = __bfloat162float(h1b[m3.x * HID_DIM + lane]);
            float v4 = __bfloat162float(h1b[m4.x * HID_DIM + lane]);
            float v5 = __bfloat162float(h1b[m5.x * HID_DIM + lane]);
            float v6 = __bfloat162float(h1b[m6.x * HID_DIM + lane]);
            float v7 = __bfloat162float(h1b[m7.x * HID_DIM + lane]);
            acc0 += __int_as_float(m0.y) * v0;
            acc1 += __int_as_float(m1.y) * v1;
            acc2 += __int_as_float(m2.y) * v2;
            acc3 += __int_as_float(m3.y) * v3;
            acc0 += __int_as_float(m4.y) * v4;
            acc1 += __int_as_float(m5.y) * v5;
            acc2 += __int_as_float(m6.y) * v6;
            acc3 += __int_as_float(m7.y) * v7;
        }
        for (; j + 2 <= cnt; j += 2) {
            int2 m0 = meta[wl][j + 0];
            int2 m1 = meta[wl][j + 1];
            float v0 = __bfloat162float(h1b[m0.x * HID_DIM + lane]);
            float v1 = __bfloat162float(h1b[m1.x * HID_DIM + lane]);
            acc0 += __int_as_float(m0.y) * v0;
            acc1 += __int_as_float(m1.y) * v1;
        }
        if (j < cnt) {
            int2 m = meta[wl][j];
            acc0 += __int_as_float(m.y) * __bfloat162float(h1b[m.x * HID_DIM + lane]);
        }
        __builtin_amdgcn_wave_barrier();
    }
    float di = dinv[wave];
    float self = __bfloat162float(h1b[wave * HID_DIM + lane]);   // unscaled
    float z = di * (acc0 + acc1 + acc2 + acc3 + di * self) + b1[lane];
    float h = fmaxf(z, 0.0f);
    float v = h * W2[lane];
#pragma unroll
    for (int off = 32; off > 0; off >>= 1)
        v += __shfl_down(v, off, 64);
    if (lane == 0) h2s[wave] = v * di;
}

// =============== kernel 4: gather L2 + sigmoid ================================
__global__ void gather2_final_kernel(const int* __restrict__ start_g, const int* __restrict__ cnt_g,
                                     const int2* __restrict__ edge_s,
                                     const float* __restrict__ h2s, const float* __restrict__ dinv,
                                     const float* __restrict__ b2, float* __restrict__ out) {
    int n = blockIdx.x * blockDim.x + threadIdx.x;
    if (n >= N_NODES) return;
    int s0 = start_g[n];
    int s1 = s0 + cnt_g[n];
    float acc = 0.0f;
    for (int t = s0; t < s1; ++t) {
        int2 m = edge_s[t];
        acc += __int_as_float(m.y) * h2s[m.x];
    }
    float z = dinv[n] * (acc + h2s[n]) + b2[0];
    out[n] = 1.0f / (1.0f + expf(-z));
}

extern "C" void kernel_launch(void* const* d_in, const int* in_sizes, int n_in,
                              void* d_out, int out_size, void* d_ws, size_t ws_size,
                              hipStream_t stream) {
    const float* x  = (const float*)d_in[0];
    const int*   ei = (const int*)d_in[1];
    const float* ew = (const float*)d_in[2];
    const float* W1 = (const float*)d_in[3];
    const float* b1 = (const float*)d_in[4];
    const float* W2 = (const float*)d_in[5];
    const float* b2 = (const float*)d_in[6];
    float* out = (float*)d_out;

    const int* src = ei;
    const int* dst = ei + N_EDGES;

    // workspace layout (int2 arrays first for 8B alignment)
    char* ws = (char*)d_ws;
    int2*  edge_b  = (int2*)ws;              ws += (size_t)NBKT * BKT_CAP * sizeof(int2);
    int2*  edge_s  = (int2*)ws;              ws += (size_t)NBKT * BKT_CAP * sizeof(int2);
    int*   gcursor = (int*)ws;               ws += NBKT * sizeof(int);
    int*   start_g = (int*)ws;               ws += N_NODES * sizeof(int);
    int*   cnt_g   = (int*)ws;               ws += N_NODES * sizeof(int);
    float* dinv    = (float*)ws;             ws += N_NODES * sizeof(float);
    float* h2s     = (float*)ws;             ws += N_NODES * sizeof(float);
    __hip_bfloat16* h1b = (__hip_bfloat16*)ws;  // N_NODES * HID_DIM bf16

    hipMemsetAsync(gcursor, 0, NBKT * sizeof(int), stream);
    partgemm_kernel<<<NPASSC + NGEMM, 256, 0, stream>>>(src, dst, ew, gcursor, edge_b, x, W1, h1b);
    bsort_kernel<<<NBKT, 256, 0, stream>>>(gcursor, edge_b, edge_s, start_g, cnt_g, dinv);
    gather1_layer2_kernel<<<(N_NODES * 64) / 256, 256, 0, stream>>>(start_g, cnt_g, edge_s, h1b, dinv, b1, W2, h2s);
    gather2_final_kernel<<<(N_NODES + 255) / 256, 256, 0, stream>>>(start_g, cnt_g, edge_s, h2s, dinv, b2, out);
}